// Round 3
// baseline (1156.935 us; speedup 1.0000x reference)
//
#include <hip/hip_runtime.h>

// LightGCN propagation on MI355X (gfx950).
//   h_{k+1}[r,:] = sum_{e: row[e]==r} val[e] * h_k[col[e],:]   D=32
//   out = (x + h1 + h2 + h3) / 4
//
// Round 3: R2's CSR scatter-pack had 8x write amplification (8B records to
// atomic-cursor-random destinations -> 100 MB HBM writeback, 116 us).
// Replace the global counting sort with a chunk-local multisplit:
//   - partition_kernel: each block takes 4096 consecutive edges, LDS-
//     histograms them into 391 row-buckets (256 rows each), LDS-scans,
//     reorders into an LDS stage, writes back contiguously at its own
//     chunk offset (coalesced, amp 1.0, no global atomics, no prepasses).
//     Per-(chunk,bucket) segment offsets -> off[chunk][bucket].
//   - spmm_kernel<MODE>: one block per bucket, 32 KB LDS accumulator
//     (256 rows x 32 feats), half-waves walk the bucket's 391 chunk
//     segments edge-parallel, ds_add_f32 LDS atomics (bank-aliasing is
//     2-way = free), coalesced epilogue fused with layer accumulation.

#define NN 100000
#define NE 1600000
#define DD 32
#define CHUNK 4096
#define NCHUNK ((NE + CHUNK - 1) / CHUNK)   // 391
#define BROWS 256                           // rows per bucket
#define NBKT ((NN + BROWS - 1) / BROWS)     // 391
#define OFFW (NBKT + 1)                     // 392

// ---- chunk-local multisplit ----------------------------------------------

__global__ __launch_bounds__(512) void partition_kernel(
    const int* __restrict__ row, const int* __restrict__ col,
    const float* __restrict__ val,
    int* __restrict__ off, int2* __restrict__ edges)
{
    __shared__ int  cnt[NBKT];
    __shared__ int  cur[NBKT];
    __shared__ int  wtot[8];
    __shared__ int2 stage[CHUNK];           // 32 KB
    const int tid   = threadIdx.x;
    const int c     = blockIdx.x;
    const int start = c * CHUNK;
    const int n     = min(CHUNK, NE - start);

    for (int i = tid; i < NBKT; i += 512) cnt[i] = 0;
    __syncthreads();

    int rcache[CHUNK / 512];                // 8 rows cached in registers
    #pragma unroll
    for (int k = 0; k < CHUNK / 512; k++) {
        int j = k * 512 + tid;
        int r = (j < n) ? row[start + j] : -1;
        rcache[k] = r;
        if (r >= 0) atomicAdd(&cnt[r >> 8], 1);
    }
    __syncthreads();

    // exclusive scan of cnt[0..391) with 512 threads (wave64 shuffle scan)
    int v = (tid < NBKT) ? cnt[tid] : 0;
    int lane = tid & 63, w = tid >> 6;
    int x = v;
    #pragma unroll
    for (int o2 = 1; o2 < 64; o2 <<= 1) {
        int y = __shfl_up(x, o2, 64);
        if (lane >= o2) x += y;
    }
    if (lane == 63) wtot[w] = x;
    __syncthreads();
    int wo = 0;
    #pragma unroll
    for (int w2 = 0; w2 < 8; w2++) if (w2 < w) wo += wtot[w2];
    int excl = x + wo - v;
    if (tid < NBKT) { cur[tid] = excl; off[(size_t)c * OFFW + tid] = excl; }
    if (tid == 0)   off[(size_t)c * OFFW + NBKT] = n;
    __syncthreads();

    // place: bucket-sorted order within the chunk (order inside bucket is
    // atomic-arbitrary -- fp32 sum order is free to vary, threshold 0.4)
    #pragma unroll
    for (int k = 0; k < CHUNK / 512; k++) {
        int j = k * 512 + tid;
        int r = rcache[k];
        if (r >= 0) {
            int b = r >> 8;
            int pos = atomicAdd(&cur[b], 1);
            stage[pos] = make_int2(((r & 255) << 17) | col[start + j],
                                   __float_as_int(val[start + j]));
        }
    }
    __syncthreads();

    // flush contiguously at this chunk's own offset -- fully coalesced
    #pragma unroll
    for (int k = 0; k < CHUNK / 512; k++) {
        int j = k * 512 + tid;
        if (j < n) edges[(size_t)start + j] = stage[j];
    }
}

// ---- bucketed LDS-accumulate SpMM ----------------------------------------
// MODE 0: hout = A x          ; out  = x + hout
// MODE 1: hout = A hin        ; out += hout
// MODE 2: (last) out = (out + A hin) * 0.25

template <int MODE>
__global__ __launch_bounds__(1024) void spmm_kernel(
    const int* __restrict__ off, const int2* __restrict__ edges,
    const float* __restrict__ hin, float* __restrict__ hout,
    const float* __restrict__ xin, float* __restrict__ outp)
{
    __shared__ float lacc[BROWS * DD];      // 32 KB accumulator
    const int tid = threadIdx.x;
    const int b   = blockIdx.x;

    #pragma unroll
    for (int k = 0; k < (BROWS * DD) / 1024; k++) lacc[k * 1024 + tid] = 0.f;
    __syncthreads();

    const int hw = tid >> 5;                // 0..31 half-waves
    const int d  = tid & 31;                // feature lane
    for (int c = hw; c < NCHUNK; c += 32) {
        const int* orow = off + (size_t)c * OFFW;
        int s = orow[b];
        int e = orow[b + 1];
        const int2* eb = edges + (size_t)c * CHUNK;
        int i = s;
        for (; i + 2 <= e; i += 2) {        // 2 independent gathers in flight
            int2 a0 = eb[i];
            int2 a1 = eb[i + 1];
            float g0 = hin[((size_t)(a0.x & 0x1FFFF) << 5) + d];
            float g1 = hin[((size_t)(a1.x & 0x1FFFF) << 5) + d];
            atomicAdd(&lacc[((a0.x >> 17) << 5) + d], __int_as_float(a0.y) * g0);
            atomicAdd(&lacc[((a1.x >> 17) << 5) + d], __int_as_float(a1.y) * g1);
        }
        if (i < e) {
            int2 a0 = eb[i];
            float g0 = hin[((size_t)(a0.x & 0x1FFFF) << 5) + d];
            atomicAdd(&lacc[((a0.x >> 17) << 5) + d], __int_as_float(a0.y) * g0);
        }
    }
    __syncthreads();

    const size_t base = (size_t)b * (BROWS * DD);
    const size_t lim  = (size_t)NN * DD;
    #pragma unroll
    for (int k = 0; k < (BROWS * DD) / 1024; k++) {
        int idx = k * 1024 + tid;
        size_t o = base + idx;
        if (o < lim) {
            float a = lacc[idx];
            if (MODE == 0)      { hout[o] = a; outp[o] = xin[o] + a; }
            else if (MODE == 1) { hout[o] = a; outp[o] = outp[o] + a; }
            else                { outp[o] = (outp[o] + a) * 0.25f; }
        }
    }
}

// ---- launch ---------------------------------------------------------------

extern "C" void kernel_launch(void* const* d_in, const int* in_sizes, int n_in,
                              void* d_out, int out_size, void* d_ws, size_t ws_size,
                              hipStream_t stream) {
    const int*   edge_row = (const int*)d_in[0];
    const int*   edge_col = (const int*)d_in[1];
    const float* edge_val = (const float*)d_in[2];
    const float* x        = (const float*)d_in[3];
    float* out = (float*)d_out;

    char* ws = (char*)d_ws;
    const size_t off_bytes = ((size_t)NCHUNK * OFFW * 4 + 4095) & ~4095ull; // ~614 KB
    int*  off   = (int*)ws;
    int2* edges = (int2*)(ws + off_bytes);                                  // 12.8 MB
    float* h0   = (float*)(ws + off_bytes + (size_t)NE * 8);                // 12.8 MB
    float* h1   = (float*)(ws + off_bytes + (size_t)NE * 8 + (size_t)NN * DD * 4);

    partition_kernel<<<NCHUNK, 512, 0, stream>>>(edge_row, edge_col, edge_val,
                                                 off, edges);
    spmm_kernel<0><<<NBKT, 1024, 0, stream>>>(off, edges, x,  h0, x, out);
    spmm_kernel<1><<<NBKT, 1024, 0, stream>>>(off, edges, h0, h1, x, out);
    spmm_kernel<2><<<NBKT, 1024, 0, stream>>>(off, edges, h1, h0, x, out);
}

// Round 4
// 1147.796 us; speedup vs baseline: 1.0080x; 1.0080x over previous
//
#include <hip/hip_runtime.h>

// LightGCN propagation on MI355X (gfx950).
//   h_{k+1}[r,:] = sum_{e: row[e]==r} val[e] * h_k[col[e],:]   D=32
//   out = (x + h1 + h2 + h3) / 4
//
// Round 4: R3's bucketed-LDS SpMM was latency-bound (VALUBusy 4.7%) because
// each block walked 391 tiny chunk-segments with dependent offset loads.
// Fix: 3-pass bucket sort makes each bucket's edges GLOBALLY CONTIGUOUS:
//   hist  : per-chunk LDS histogram -> global bucket totals (782 atomics/blk)
//   scan  : one block: exclusive scan -> bucketbase + write cursors
//   scatter: per-chunk LDS multisplit, ONE global atomicAdd per nonempty
//            (chunk,bucket) segment reserves a contiguous slot, direct
//            writes (avg 42 B/segment -> ~2.5x amp = ~32 MB, vs R2's 100 MB)
//   spmm<MODE> x3: block per bucket (782 blocks, 256 thr, 16 KB LDS acc ->
//            8 blocks/CU capacity, grid fully resident), 8 half-waves
//            stride one coalesced edge run with 4 gathers in flight,
//            ds_add_f32 accumulate, epilogue fused with layer accumulation.

#define NN 100000
#define NE 1600000
#define DD 32
#define CHUNK 4096
#define NCHUNK ((NE + CHUNK - 1) / CHUNK)   // 391
#define BROWS 128
#define NBKT ((NN + BROWS - 1) / BROWS)     // 782

// ---- pass 1: bucket histogram --------------------------------------------

__global__ __launch_bounds__(1024) void hist_kernel(
    const int* __restrict__ row, int* __restrict__ bucket_tot)
{
    __shared__ int cnt[NBKT];
    const int tid = threadIdx.x;
    const int start = blockIdx.x * CHUNK;
    const int n = min(CHUNK, NE - start);
    for (int k = tid; k < NBKT; k += 1024) cnt[k] = 0;
    __syncthreads();
    #pragma unroll
    for (int k = 0; k < CHUNK / 1024; k++) {
        int j = k * 1024 + tid;
        if (j < n) atomicAdd(&cnt[row[start + j] >> 7], 1);
    }
    __syncthreads();
    for (int k = tid; k < NBKT; k += 1024)
        if (cnt[k]) atomicAdd(&bucket_tot[k], cnt[k]);
}

// ---- pass 2: exclusive scan of 782 bucket totals -> base + cursors -------

__global__ __launch_bounds__(1024) void scan_kernel(
    const int* __restrict__ tot, int* __restrict__ bucketbase,
    int* __restrict__ cursor)
{
    const int tid = threadIdx.x;
    int v = (tid < NBKT) ? tot[tid] : 0;
    int lane = tid & 63, w = tid >> 6;          // 16 waves
    int x = v;
    #pragma unroll
    for (int off = 1; off < 64; off <<= 1) {
        int y = __shfl_up(x, off, 64);
        if (lane >= off) x += y;
    }
    __shared__ int wt[16];
    if (lane == 63) wt[w] = x;
    __syncthreads();
    if (w == 0 && lane < 16) {
        int y = wt[lane];
        #pragma unroll
        for (int off = 1; off < 16; off <<= 1) {
            int z = __shfl_up(y, off, 16);
            if ((lane & 15) >= off) y += z;
        }
        wt[lane] = y;                            // inclusive wave totals
    }
    __syncthreads();
    int wo = (w > 0) ? wt[w - 1] : 0;
    int excl = x + wo - v;
    if (tid < NBKT) { bucketbase[tid] = excl; cursor[tid] = excl; }
    if (tid == NBKT) bucketbase[NBKT] = NE;
}

// ---- pass 3: multisplit scatter into bucket-contiguous layout ------------

__global__ __launch_bounds__(1024) void scatter_kernel(
    const int* __restrict__ row, const int* __restrict__ col,
    const float* __restrict__ val, int* __restrict__ cursor,
    int2* __restrict__ edges)
{
    __shared__ int cnt[NBKT];
    __shared__ int gofs[NBKT];
    const int tid = threadIdx.x;
    const int start = blockIdx.x * CHUNK;
    const int n = min(CHUNK, NE - start);
    for (int k = tid; k < NBKT; k += 1024) cnt[k] = 0;
    __syncthreads();

    int rrow[CHUNK / 1024], rank[CHUNK / 1024];
    #pragma unroll
    for (int k = 0; k < CHUNK / 1024; k++) {
        int j = k * 1024 + tid;
        int r = (j < n) ? row[start + j] : -1;
        rrow[k] = r;
        rank[k] = (r >= 0) ? atomicAdd(&cnt[r >> 7], 1) : 0;
    }
    __syncthreads();
    // reserve one contiguous global slot per nonempty bucket segment
    for (int k = tid; k < NBKT; k += 1024)
        if (cnt[k]) gofs[k] = atomicAdd(&cursor[k], cnt[k]);
    __syncthreads();
    #pragma unroll
    for (int k = 0; k < CHUNK / 1024; k++) {
        int j = k * 1024 + tid;
        int r = rrow[k];
        if (r >= 0) {
            int b = r >> 7;
            edges[gofs[b] + rank[k]] =
                make_int2(((r & 127) << 17) | col[start + j],
                          __float_as_int(val[start + j]));
        }
    }
}

// ---- bucketed LDS-accumulate SpMM (contiguous edge run per block) --------
// MODE 0: hout = A x   ; out  = x + hout
// MODE 1: hout = A hin ; out += hout
// MODE 2: out = (out + A hin) * 0.25

template <int MODE>
__global__ __launch_bounds__(256) void spmm_kernel(
    const int* __restrict__ bucketbase, const int2* __restrict__ edges,
    const float* __restrict__ hin, float* __restrict__ hout,
    const float* __restrict__ xin, float* __restrict__ outp)
{
    __shared__ float lacc[BROWS * DD];      // 16 KB
    const int tid = threadIdx.x;
    const int b   = blockIdx.x;
    #pragma unroll
    for (int k = 0; k < (BROWS * DD) / 256; k++) lacc[k * 256 + tid] = 0.f;
    __syncthreads();

    const int hw = tid >> 5;                // 8 half-waves
    const int d  = tid & 31;
    const int s = bucketbase[b];
    const int e = bucketbase[b + 1];

    int i = s + hw * 4;
    for (; i + 4 <= e; i += 32) {           // 4 independent gathers in flight
        int2 a0 = edges[i];
        int2 a1 = edges[i + 1];
        int2 a2 = edges[i + 2];
        int2 a3 = edges[i + 3];
        float g0 = hin[((a0.x & 0x1FFFF) << 5) + d];
        float g1 = hin[((a1.x & 0x1FFFF) << 5) + d];
        float g2 = hin[((a2.x & 0x1FFFF) << 5) + d];
        float g3 = hin[((a3.x & 0x1FFFF) << 5) + d];
        atomicAdd(&lacc[((a0.x >> 17) << 5) + d], __int_as_float(a0.y) * g0);
        atomicAdd(&lacc[((a1.x >> 17) << 5) + d], __int_as_float(a1.y) * g1);
        atomicAdd(&lacc[((a2.x >> 17) << 5) + d], __int_as_float(a2.y) * g2);
        atomicAdd(&lacc[((a3.x >> 17) << 5) + d], __int_as_float(a3.y) * g3);
    }
    for (; i < e; ++i) {                    // partial quad tail (<=3)
        int2 a0 = edges[i];
        float g0 = hin[((a0.x & 0x1FFFF) << 5) + d];
        atomicAdd(&lacc[((a0.x >> 17) << 5) + d], __int_as_float(a0.y) * g0);
    }
    __syncthreads();

    const int  base = b * (BROWS * DD);
    const int  lim  = NN * DD;
    #pragma unroll
    for (int k = 0; k < (BROWS * DD) / 256; k++) {
        int idx = k * 256 + tid;
        int o = base + idx;
        if (o < lim) {
            float a = lacc[idx];
            if (MODE == 0)      { hout[o] = a; outp[o] = xin[o] + a; }
            else if (MODE == 1) { hout[o] = a; outp[o] = outp[o] + a; }
            else                { outp[o] = (outp[o] + a) * 0.25f; }
        }
    }
}

// ---- launch ---------------------------------------------------------------

extern "C" void kernel_launch(void* const* d_in, const int* in_sizes, int n_in,
                              void* d_out, int out_size, void* d_ws, size_t ws_size,
                              hipStream_t stream) {
    const int*   edge_row = (const int*)d_in[0];
    const int*   edge_col = (const int*)d_in[1];
    const float* edge_val = (const float*)d_in[2];
    const float* x        = (const float*)d_in[3];
    float* out = (float*)d_out;

    char* ws = (char*)d_ws;
    int*  bucket_tot = (int*)ws;                          ws += 4096;
    int*  bucketbase = (int*)ws;                          ws += 4096;
    int*  cursor     = (int*)ws;                          ws += 4096;
    int2* edges      = (int2*)ws;                         ws += (size_t)NE * 8;  // 12.8 MB
    float* h0        = (float*)ws;                        ws += (size_t)NN * DD * 4;
    float* h1        = (float*)ws;

    hipMemsetAsync(bucket_tot, 0, NBKT * sizeof(int), stream);
    hist_kernel   <<<NCHUNK, 1024, 0, stream>>>(edge_row, bucket_tot);
    scan_kernel   <<<1, 1024, 0, stream>>>(bucket_tot, bucketbase, cursor);
    scatter_kernel<<<NCHUNK, 1024, 0, stream>>>(edge_row, edge_col, edge_val,
                                                cursor, edges);

    spmm_kernel<0><<<NBKT, 256, 0, stream>>>(bucketbase, edges, x,  h0, x, out);
    spmm_kernel<1><<<NBKT, 256, 0, stream>>>(bucketbase, edges, h0, h1, x, out);
    spmm_kernel<2><<<NBKT, 256, 0, stream>>>(bucketbase, edges, h1, h0, x, out);
}

// Round 5
// 1135.493 us; speedup vs baseline: 1.0189x; 1.0108x over previous
//
#include <hip/hip_runtime.h>

// LightGCN propagation on MI355X (gfx950).
//   h_{k+1}[r,:] = sum_{e: row[e]==r} val[e] * h_k[col[e],:]   D=32
//   out = (x + h1 + h2 + h3) / 4
//
// Round 5: R4's spmm was latency-starved (Occupancy 21%, VALUBusy 3.2%):
// 256-thr blocks on 782 buckets left ~12 waves/CU with only 4 gathers in
// flight per half-wave. Same structure, restored parallelism:
//   - 512-thr spmm blocks (16 half-waves): 782 blocks ~ 3/CU resident,
//     ~24 waves/CU (CU capacity 4 blocks x 8 waves; 4 x 16 KB LDS = 64 KB).
//   - 8 independent gathers in flight per half-wave (batched edge loads).
// Per-CU outstanding gathers 96 -> ~384: latency-bound -> throughput-bound.
// Build pipeline (hist/scan/scatter, off top-5 at R4) unchanged.

#define NN 100000
#define NE 1600000
#define DD 32
#define CHUNK 4096
#define NCHUNK ((NE + CHUNK - 1) / CHUNK)   // 391
#define BROWS 128
#define NBKT ((NN + BROWS - 1) / BROWS)     // 782

// ---- pass 1: bucket histogram --------------------------------------------

__global__ __launch_bounds__(1024) void hist_kernel(
    const int* __restrict__ row, int* __restrict__ bucket_tot)
{
    __shared__ int cnt[NBKT];
    const int tid = threadIdx.x;
    const int start = blockIdx.x * CHUNK;
    const int n = min(CHUNK, NE - start);
    for (int k = tid; k < NBKT; k += 1024) cnt[k] = 0;
    __syncthreads();
    #pragma unroll
    for (int k = 0; k < CHUNK / 1024; k++) {
        int j = k * 1024 + tid;
        if (j < n) atomicAdd(&cnt[row[start + j] >> 7], 1);
    }
    __syncthreads();
    for (int k = tid; k < NBKT; k += 1024)
        if (cnt[k]) atomicAdd(&bucket_tot[k], cnt[k]);
}

// ---- pass 2: exclusive scan of 782 bucket totals -> base + cursors -------

__global__ __launch_bounds__(1024) void scan_kernel(
    const int* __restrict__ tot, int* __restrict__ bucketbase,
    int* __restrict__ cursor)
{
    const int tid = threadIdx.x;
    int v = (tid < NBKT) ? tot[tid] : 0;
    int lane = tid & 63, w = tid >> 6;          // 16 waves
    int x = v;
    #pragma unroll
    for (int off = 1; off < 64; off <<= 1) {
        int y = __shfl_up(x, off, 64);
        if (lane >= off) x += y;
    }
    __shared__ int wt[16];
    if (lane == 63) wt[w] = x;
    __syncthreads();
    if (w == 0 && lane < 16) {
        int y = wt[lane];
        #pragma unroll
        for (int off = 1; off < 16; off <<= 1) {
            int z = __shfl_up(y, off, 16);
            if ((lane & 15) >= off) y += z;
        }
        wt[lane] = y;                            // inclusive wave totals
    }
    __syncthreads();
    int wo = (w > 0) ? wt[w - 1] : 0;
    int excl = x + wo - v;
    if (tid < NBKT) { bucketbase[tid] = excl; cursor[tid] = excl; }
    if (tid == NBKT) bucketbase[NBKT] = NE;
}

// ---- pass 3: multisplit scatter into bucket-contiguous layout ------------

__global__ __launch_bounds__(1024) void scatter_kernel(
    const int* __restrict__ row, const int* __restrict__ col,
    const float* __restrict__ val, int* __restrict__ cursor,
    int2* __restrict__ edges)
{
    __shared__ int cnt[NBKT];
    __shared__ int gofs[NBKT];
    const int tid = threadIdx.x;
    const int start = blockIdx.x * CHUNK;
    const int n = min(CHUNK, NE - start);
    for (int k = tid; k < NBKT; k += 1024) cnt[k] = 0;
    __syncthreads();

    int rrow[CHUNK / 1024], rank[CHUNK / 1024];
    #pragma unroll
    for (int k = 0; k < CHUNK / 1024; k++) {
        int j = k * 1024 + tid;
        int r = (j < n) ? row[start + j] : -1;
        rrow[k] = r;
        rank[k] = (r >= 0) ? atomicAdd(&cnt[r >> 7], 1) : 0;
    }
    __syncthreads();
    // reserve one contiguous global slot per nonempty bucket segment
    for (int k = tid; k < NBKT; k += 1024)
        if (cnt[k]) gofs[k] = atomicAdd(&cursor[k], cnt[k]);
    __syncthreads();
    #pragma unroll
    for (int k = 0; k < CHUNK / 1024; k++) {
        int j = k * 1024 + tid;
        int r = rrow[k];
        if (r >= 0) {
            int b = r >> 7;
            edges[gofs[b] + rank[k]] =
                make_int2(((r & 127) << 17) | col[start + j],
                          __float_as_int(val[start + j]));
        }
    }
}

// ---- bucketed LDS-accumulate SpMM (contiguous edge run per block) --------
// MODE 0: hout = A x   ; out  = x + hout
// MODE 1: hout = A hin ; out += hout
// MODE 2: out = (out + A hin) * 0.25

template <int MODE>
__global__ __launch_bounds__(512) void spmm_kernel(
    const int* __restrict__ bucketbase, const int2* __restrict__ edges,
    const float* __restrict__ hin, float* __restrict__ hout,
    const float* __restrict__ xin, float* __restrict__ outp)
{
    __shared__ float lacc[BROWS * DD];      // 16 KB
    const int tid = threadIdx.x;
    const int b   = blockIdx.x;
    #pragma unroll
    for (int k = 0; k < (BROWS * DD) / 512; k++) lacc[k * 512 + tid] = 0.f;
    __syncthreads();

    const int hw = tid >> 5;                // 16 half-waves
    const int d  = tid & 31;
    const int s = bucketbase[b];
    const int e = bucketbase[b + 1];

    // 8 independent gathers in flight per half-wave; exactly one half-wave
    // (owner of the first incomplete octet) picks up the <8-edge tail.
    int i = s + hw * 8;
    for (; i + 8 <= e; i += 16 * 8) {
        int2 a[8];
        #pragma unroll
        for (int q = 0; q < 8; q++) a[q] = edges[i + q];
        float g[8];
        #pragma unroll
        for (int q = 0; q < 8; q++)
            g[q] = hin[((a[q].x & 0x1FFFF) << 5) + d];
        #pragma unroll
        for (int q = 0; q < 8; q++)
            atomicAdd(&lacc[((a[q].x >> 17) << 5) + d],
                      __int_as_float(a[q].y) * g[q]);
    }
    for (; i < e; ++i) {
        int2 a0 = edges[i];
        float g0 = hin[((a0.x & 0x1FFFF) << 5) + d];
        atomicAdd(&lacc[((a0.x >> 17) << 5) + d], __int_as_float(a0.y) * g0);
    }
    __syncthreads();

    const int base = b * (BROWS * DD);
    const int lim  = NN * DD;
    #pragma unroll
    for (int k = 0; k < (BROWS * DD) / 512; k++) {
        int idx = k * 512 + tid;
        int o = base + idx;
        if (o < lim) {
            float a = lacc[idx];
            if (MODE == 0)      { hout[o] = a; outp[o] = xin[o] + a; }
            else if (MODE == 1) { hout[o] = a; outp[o] = outp[o] + a; }
            else                { outp[o] = (outp[o] + a) * 0.25f; }
        }
    }
}

// ---- launch ---------------------------------------------------------------

extern "C" void kernel_launch(void* const* d_in, const int* in_sizes, int n_in,
                              void* d_out, int out_size, void* d_ws, size_t ws_size,
                              hipStream_t stream) {
    const int*   edge_row = (const int*)d_in[0];
    const int*   edge_col = (const int*)d_in[1];
    const float* edge_val = (const float*)d_in[2];
    const float* x        = (const float*)d_in[3];
    float* out = (float*)d_out;

    char* ws = (char*)d_ws;
    int*  bucket_tot = (int*)ws;                          ws += 4096;
    int*  bucketbase = (int*)ws;                          ws += 4096;
    int*  cursor     = (int*)ws;                          ws += 4096;
    int2* edges      = (int2*)ws;                         ws += (size_t)NE * 8;  // 12.8 MB
    float* h0        = (float*)ws;                        ws += (size_t)NN * DD * 4;
    float* h1        = (float*)ws;

    hipMemsetAsync(bucket_tot, 0, NBKT * sizeof(int), stream);
    hist_kernel   <<<NCHUNK, 1024, 0, stream>>>(edge_row, bucket_tot);
    scan_kernel   <<<1, 1024, 0, stream>>>(bucket_tot, bucketbase, cursor);
    scatter_kernel<<<NCHUNK, 1024, 0, stream>>>(edge_row, edge_col, edge_val,
                                                cursor, edges);

    spmm_kernel<0><<<NBKT, 512, 0, stream>>>(bucketbase, edges, x,  h0, x, out);
    spmm_kernel<1><<<NBKT, 512, 0, stream>>>(bucketbase, edges, h0, h1, x, out);
    spmm_kernel<2><<<NBKT, 512, 0, stream>>>(bucketbase, edges, h1, h0, x, out);
}

// Round 6
// 220.118 us; speedup vs baseline: 5.2560x; 5.1586x over previous
//
#include <hip/hip_runtime.h>

// LightGCN propagation on MI355X (gfx950).
//   h_{k+1}[r,:] = sum_{e: row[e]==r} val[e] * h_k[col[e],:]   D=32
//   out = (x + h1 + h2 + h3) / 4
//
// Round 6: R4/R5 proved the spmm is pinned at ~132 CU-cyc/edge regardless of
// occupancy or load depth -> per-edge wave-instruction cost is the limiter
// (half-wave-per-edge = 1.5 VMEM insts + 1 LDS-atomic per edge, all pipes
// <5% busy). Fix: 8-lane groups with float4 lanes over row-sorted CSR:
//   - one gather inst = 64 lanes x 16 B = 8 edges' full 128 B rows
//   - register accumulation (group owns the row) -> zero LDS, zero atomics
//   - ~0.19 VMEM + 0.5 VALU wave-insts per edge (~8x fewer than R5)
//   - 12.5k waves (3125 blocks) -> deep per-CU queues
// Build: R5 hist/scan/scatter (bucket-contiguous) + new bucket_sort pass
// (block per 128-row bucket: LDS hist+scan -> row_ptr, rewrite row-sorted;
// scattered 8 B writes stay inside a 16 KB hot region -> ~1x write amp).

#define NN 100000
#define NE 1600000
#define DD 32
#define CHUNK 4096
#define NCHUNK ((NE + CHUNK - 1) / CHUNK)   // 391
#define BROWS 128
#define NBKT ((NN + BROWS - 1) / BROWS)     // 782

// ---- pass 1: bucket histogram --------------------------------------------

__global__ __launch_bounds__(1024) void hist_kernel(
    const int* __restrict__ row, int* __restrict__ bucket_tot)
{
    __shared__ int cnt[NBKT];
    const int tid = threadIdx.x;
    const int start = blockIdx.x * CHUNK;
    const int n = min(CHUNK, NE - start);
    for (int k = tid; k < NBKT; k += 1024) cnt[k] = 0;
    __syncthreads();
    #pragma unroll
    for (int k = 0; k < CHUNK / 1024; k++) {
        int j = k * 1024 + tid;
        if (j < n) atomicAdd(&cnt[row[start + j] >> 7], 1);
    }
    __syncthreads();
    for (int k = tid; k < NBKT; k += 1024)
        if (cnt[k]) atomicAdd(&bucket_tot[k], cnt[k]);
}

// ---- pass 2: exclusive scan of 782 bucket totals -> base + cursors -------

__global__ __launch_bounds__(1024) void scan_kernel(
    const int* __restrict__ tot, int* __restrict__ bucketbase,
    int* __restrict__ cursor, int* __restrict__ row_ptr)
{
    const int tid = threadIdx.x;
    int v = (tid < NBKT) ? tot[tid] : 0;
    int lane = tid & 63, w = tid >> 6;          // 16 waves
    int x = v;
    #pragma unroll
    for (int off = 1; off < 64; off <<= 1) {
        int y = __shfl_up(x, off, 64);
        if (lane >= off) x += y;
    }
    __shared__ int wt[16];
    if (lane == 63) wt[w] = x;
    __syncthreads();
    if (w == 0 && lane < 16) {
        int y = wt[lane];
        #pragma unroll
        for (int off = 1; off < 16; off <<= 1) {
            int z = __shfl_up(y, off, 16);
            if ((lane & 15) >= off) y += z;
        }
        wt[lane] = y;                            // inclusive wave totals
    }
    __syncthreads();
    int wo = (w > 0) ? wt[w - 1] : 0;
    int excl = x + wo - v;
    if (tid < NBKT) { bucketbase[tid] = excl; cursor[tid] = excl; }
    if (tid == NBKT) { bucketbase[NBKT] = NE; row_ptr[NN] = NE; }
}

// ---- pass 3: multisplit scatter into bucket-contiguous layout ------------
// record: ((row & 127) << 17) | col   (col < 2^17), val bits in .y

__global__ __launch_bounds__(1024) void scatter_kernel(
    const int* __restrict__ row, const int* __restrict__ col,
    const float* __restrict__ val, int* __restrict__ cursor,
    int2* __restrict__ tmp)
{
    __shared__ int cnt[NBKT];
    __shared__ int gofs[NBKT];
    const int tid = threadIdx.x;
    const int start = blockIdx.x * CHUNK;
    const int n = min(CHUNK, NE - start);
    for (int k = tid; k < NBKT; k += 1024) cnt[k] = 0;
    __syncthreads();

    int rrow[CHUNK / 1024], rank[CHUNK / 1024];
    #pragma unroll
    for (int k = 0; k < CHUNK / 1024; k++) {
        int j = k * 1024 + tid;
        int r = (j < n) ? row[start + j] : -1;
        rrow[k] = r;
        rank[k] = (r >= 0) ? atomicAdd(&cnt[r >> 7], 1) : 0;
    }
    __syncthreads();
    for (int k = tid; k < NBKT; k += 1024)
        if (cnt[k]) gofs[k] = atomicAdd(&cursor[k], cnt[k]);
    __syncthreads();
    #pragma unroll
    for (int k = 0; k < CHUNK / 1024; k++) {
        int j = k * 1024 + tid;
        int r = rrow[k];
        if (r >= 0) {
            int b = r >> 7;
            tmp[gofs[b] + rank[k]] =
                make_int2(((r & 127) << 17) | col[start + j],
                          __float_as_int(val[start + j]));
        }
    }
}

// ---- pass 4: per-bucket row sort -> CSR row_ptr + clean (col,val) --------

__global__ __launch_bounds__(512) void bucket_sort_kernel(
    const int* __restrict__ bucketbase, const int2* __restrict__ tmp,
    int* __restrict__ row_ptr, int2* __restrict__ edges)
{
    __shared__ int cnt[BROWS];
    __shared__ int cur[BROWS];
    __shared__ int wt2[2];
    const int tid = threadIdx.x;
    const int b   = blockIdx.x;
    const int s   = bucketbase[b];
    const int e   = bucketbase[b + 1];

    if (tid < BROWS) cnt[tid] = 0;
    __syncthreads();
    for (int j = s + tid; j < e; j += 512)
        atomicAdd(&cnt[tmp[j].x >> 17], 1);
    __syncthreads();

    // exclusive scan of 128 counts (waves 0,1)
    int v = 0, x = 0;
    if (tid < BROWS) {
        v = cnt[tid];
        int lane = tid & 63;
        x = v;
        #pragma unroll
        for (int off = 1; off < 64; off <<= 1) {
            int y = __shfl_up(x, off, 64);
            if (lane >= off) x += y;
        }
        if (lane == 63) wt2[tid >> 6] = x;
    }
    __syncthreads();
    if (tid < BROWS) {
        int excl = x + ((tid >> 6) ? wt2[0] : 0) - v;
        cur[tid] = excl;
        int r = b * BROWS + tid;
        if (r < NN) row_ptr[r] = s + excl;
    }
    __syncthreads();

    for (int j = s + tid; j < e; j += 512) {
        int2 rec = tmp[j];
        int pos = s + atomicAdd(&cur[rec.x >> 17], 1);
        edges[pos] = make_int2(rec.x & 0x1FFFF, rec.y);
    }
}

// ---- CSR SpMM: 8-lane group per row, float4 lanes, register accumulate ---
// MODE 0: hout = A x   ; out  = x + hout
// MODE 1: hout = A hin ; out += hout
// MODE 2: out = (out + A hin) * 0.25

template <int MODE>
__global__ __launch_bounds__(256) void spmm_kernel(
    const int* __restrict__ row_ptr, const int2* __restrict__ edges,
    const float4* __restrict__ hin4, float4* __restrict__ hout4,
    const float4* __restrict__ xin4, float4* __restrict__ out4)
{
    const int g = blockIdx.x * 32 + (threadIdx.x >> 3);   // row
    if (g >= NN) return;
    const int t = threadIdx.x & 7;                        // float4 lane
    const int s = row_ptr[g];
    const int e = row_ptr[g + 1];

    float4 acc = make_float4(0.f, 0.f, 0.f, 0.f);
    int i = s;
    for (; i + 4 <= e; i += 4) {                          // 4 gathers in flight
        int2 a0 = edges[i];
        int2 a1 = edges[i + 1];
        int2 a2 = edges[i + 2];
        int2 a3 = edges[i + 3];
        float4 g0 = hin4[a0.x * 8 + t];
        float4 g1 = hin4[a1.x * 8 + t];
        float4 g2 = hin4[a2.x * 8 + t];
        float4 g3 = hin4[a3.x * 8 + t];
        float v0 = __int_as_float(a0.y), v1 = __int_as_float(a1.y);
        float v2 = __int_as_float(a2.y), v3 = __int_as_float(a3.y);
        acc.x += v0 * g0.x; acc.y += v0 * g0.y; acc.z += v0 * g0.z; acc.w += v0 * g0.w;
        acc.x += v1 * g1.x; acc.y += v1 * g1.y; acc.z += v1 * g1.z; acc.w += v1 * g1.w;
        acc.x += v2 * g2.x; acc.y += v2 * g2.y; acc.z += v2 * g2.z; acc.w += v2 * g2.w;
        acc.x += v3 * g3.x; acc.y += v3 * g3.y; acc.z += v3 * g3.z; acc.w += v3 * g3.w;
    }
    for (; i < e; ++i) {
        int2 a0 = edges[i];
        float4 g0 = hin4[a0.x * 8 + t];
        float v0 = __int_as_float(a0.y);
        acc.x += v0 * g0.x; acc.y += v0 * g0.y; acc.z += v0 * g0.z; acc.w += v0 * g0.w;
    }

    const int o = g * 8 + t;
    if (MODE == 0) {
        hout4[o] = acc;
        float4 xv = xin4[o];
        out4[o] = make_float4(xv.x + acc.x, xv.y + acc.y, xv.z + acc.z, xv.w + acc.w);
    } else if (MODE == 1) {
        hout4[o] = acc;
        float4 ov = out4[o];
        out4[o] = make_float4(ov.x + acc.x, ov.y + acc.y, ov.z + acc.z, ov.w + acc.w);
    } else {
        float4 ov = out4[o];
        out4[o] = make_float4((ov.x + acc.x) * 0.25f, (ov.y + acc.y) * 0.25f,
                              (ov.z + acc.z) * 0.25f, (ov.w + acc.w) * 0.25f);
    }
}

// ---- launch ---------------------------------------------------------------

extern "C" void kernel_launch(void* const* d_in, const int* in_sizes, int n_in,
                              void* d_out, int out_size, void* d_ws, size_t ws_size,
                              hipStream_t stream) {
    const int*   edge_row = (const int*)d_in[0];
    const int*   edge_col = (const int*)d_in[1];
    const float* edge_val = (const float*)d_in[2];
    const float* x        = (const float*)d_in[3];
    float* out = (float*)d_out;

    char* ws = (char*)d_ws;
    int*  bucket_tot = (int*)ws;                          ws += 4096;
    int*  bucketbase = (int*)ws;                          ws += 4096;
    int*  cursor     = (int*)ws;                          ws += 4096;
    int*  row_ptr    = (int*)ws;                          ws += ((size_t)(NN + 1) * 4 + 511) & ~511ull;
    int2* tmp        = (int2*)ws;                         ws += (size_t)NE * 8;  // 12.8 MB
    int2* edges      = (int2*)ws;                         ws += (size_t)NE * 8;  // 12.8 MB
    float* h0        = (float*)ws;                        ws += (size_t)NN * DD * 4;
    float* h1        = (float*)ws;

    hipMemsetAsync(bucket_tot, 0, NBKT * sizeof(int), stream);
    hist_kernel       <<<NCHUNK, 1024, 0, stream>>>(edge_row, bucket_tot);
    scan_kernel       <<<1, 1024, 0, stream>>>(bucket_tot, bucketbase, cursor, row_ptr);
    scatter_kernel    <<<NCHUNK, 1024, 0, stream>>>(edge_row, edge_col, edge_val,
                                                    cursor, tmp);
    bucket_sort_kernel<<<NBKT, 512, 0, stream>>>(bucketbase, tmp, row_ptr, edges);

    dim3 sp_grid((NN + 31) / 32);   // 3125 blocks, 8 lanes/row
    spmm_kernel<0><<<sp_grid, 256, 0, stream>>>(row_ptr, edges,
        (const float4*)x,  (float4*)h0, (const float4*)x, (float4*)out);
    spmm_kernel<1><<<sp_grid, 256, 0, stream>>>(row_ptr, edges,
        (const float4*)h0, (float4*)h1, (const float4*)x, (float4*)out);
    spmm_kernel<2><<<sp_grid, 256, 0, stream>>>(row_ptr, edges,
        (const float4*)h1, (float4*)h0, (const float4*)x, (float4*)out);
}